// Round 6
// baseline (350.574 us; speedup 1.0000x reference)
//
#include <hip/hip_runtime.h>

#define NN 20000
#define NE 160000
#define NEF 180000          // edges + self loops

typedef long long ll;
typedef __attribute__((ext_vector_type(4))) float f32x4;
typedef __attribute__((ext_vector_type(8))) short s16x8;

// ---------- bf16 helpers (round-to-nearest-even) ----------
static __device__ __forceinline__ float b2f(ushort u) {
  return __uint_as_float(((unsigned)u) << 16);
}
static __device__ __forceinline__ ushort f2b(float f) {
  unsigned u = __float_as_uint(f);
  return (ushort)((u + 0x7fffu + ((u >> 16) & 1u)) >> 16);
}

// ---------- bf16 MFMA GEMM: C[M,N] = A[M,K] @ Bt[N,K]^T (+bias) ----------
// 4 waves in 2x2; wave tile = (16*MF) x (16*NF) via MFMA 16x16x32 frags; no LDS.
// SCORES (GAT): per-row partial dot with att_s/att_d over this wave's 64 cols,
// 16-lane-quarter shfl reduce, atomicAdd into a_s/a_d (zeroed in k_setup).
template<int MF, int NF, bool SCORES>
__global__ __launch_bounds__(256) void gemm_mfma(
    const ushort* __restrict__ A, const ushort* __restrict__ Bt,
    const float* __restrict__ bias, ushort* __restrict__ C,
    int M, int N, int K,
    const float* __restrict__ att_s, const float* __restrict__ att_d,
    float* __restrict__ a_s, float* __restrict__ a_d)
{
  const int wid  = threadIdx.x >> 6;
  const int lane = threadIdx.x & 63;
  const int wr = wid >> 1, wc = wid & 1;
  const int bm = blockIdx.y * (32 * MF) + wr * (16 * MF);
  const int bn = blockIdx.x * (32 * NF) + wc * (16 * NF);
  const int lr = lane & 15;
  const int ko = (lane >> 4) * 8;

  const ushort* pa[MF];
  const ushort* pb[NF];
  #pragma unroll
  for (int i = 0; i < MF; i++) {
    int r = min(bm + i * 16 + lr, M - 1);
    pa[i] = A + (ll)r * K + ko;
  }
  #pragma unroll
  for (int j = 0; j < NF; j++) {
    int c = min(bn + j * 16 + lr, N - 1);
    pb[j] = Bt + (ll)c * K + ko;
  }

  f32x4 acc[MF][NF];
  #pragma unroll
  for (int i = 0; i < MF; i++)
    #pragma unroll
    for (int j = 0; j < NF; j++) acc[i][j] = {0.f, 0.f, 0.f, 0.f};

  #pragma unroll 4
  for (int k = 0; k < K; k += 32) {
    s16x8 af[MF], bf[NF];
    #pragma unroll
    for (int i = 0; i < MF; i++) af[i] = *(const s16x8*)(pa[i] + k);
    #pragma unroll
    for (int j = 0; j < NF; j++) bf[j] = *(const s16x8*)(pb[j] + k);
    #pragma unroll
    for (int i = 0; i < MF; i++)
      #pragma unroll
      for (int j = 0; j < NF; j++)
        acc[i][j] = __builtin_amdgcn_mfma_f32_16x16x32_bf16(af[i], bf[j], acc[i][j], 0, 0, 0);
  }

  const int rq = (lane >> 4) * 4;

  if (SCORES) {            // head is uniform per wave (bn 64-aligned, NF=4)
    int h = bn >> 7;
    float as[NF], ad[NF];
    #pragma unroll
    for (int j = 0; j < NF; j++) {
      as[j] = att_s[bn + j * 16 + lr];
      ad[j] = att_d[bn + j * 16 + lr];
    }
    #pragma unroll
    for (int i = 0; i < MF; i++) {
      #pragma unroll
      for (int r = 0; r < 4; r++) {
        float ss = 0.f, dd = 0.f;
        #pragma unroll
        for (int j = 0; j < NF; j++) {
          ss = fmaf(acc[i][j][r], as[j], ss);
          dd = fmaf(acc[i][j][r], ad[j], dd);
        }
        #pragma unroll
        for (int o = 1; o < 16; o <<= 1) {
          ss += __shfl_xor(ss, o);
          dd += __shfl_xor(dd, o);
        }
        int row = bm + i * 16 + rq + r;
        if (lr == 0 && row < M) {
          atomicAdd(&a_s[(ll)row * 8 + h], ss);
          atomicAdd(&a_d[(ll)row * 8 + h], dd);
        }
      }
    }
  }

  #pragma unroll
  for (int i = 0; i < MF; i++) {
    #pragma unroll
    for (int j = 0; j < NF; j++) {
      int col = bn + j * 16 + lr;
      if (col >= N) continue;
      float bv = bias ? bias[col] : 0.f;
      int rbase = bm + i * 16 + rq;
      #pragma unroll
      for (int r = 0; r < 4; r++) {
        int row = rbase + r;
        if (row >= M) continue;
        C[(ll)row * N + col] = f2b(acc[i][j][r] + bv);
      }
    }
  }
}

// ---------- fused setup: x cast, weight transpose+cast, bias packs, zeroing ----
struct PrepEnt { const float* W; ushort* Bt; int N; int K; int base; };
struct Prep { PrepEnt e[8]; int total; };

__global__ void k_setup(const float* __restrict__ x, ushort* __restrict__ xb, Prep p,
                        const float* __restrict__ b_res, const float* __restrict__ b_l1,
                        const float* __restrict__ b_l2, float* __restrict__ bias192,
                        float* __restrict__ bias256, int* __restrict__ icnt,
                        float* __restrict__ a_s, float* __restrict__ a_d) {
  ll t = (ll)blockIdx.x * 256 + threadIdx.x;
  const ll T0 = (ll)NN * 64;          // x cast: 4 floats each
  if (t < T0) {
    ll i = t * 4;
    float4 v = *(const float4*)(x + i);
    ushort4 o;
    o.x = f2b(v.x); o.y = f2b(v.y); o.z = f2b(v.z); o.w = f2b(v.w);
    *(ushort4*)(xb + i) = o;
    return;
  }
  t -= T0;
  if (t < p.total) {
    int tt = (int)t;
    #pragma unroll
    for (int i = 0; i < 8; i++) {
      int sz = p.e[i].N * p.e[i].K;
      if (tt >= p.e[i].base && tt < p.e[i].base + sz) {
        int loc = tt - p.e[i].base;
        int n = loc / p.e[i].K, k = loc - n * p.e[i].K;
        p.e[i].Bt[loc] = f2b(p.e[i].W[(ll)k * p.e[i].N + n]);
      }
    }
    return;
  }
  t -= p.total;
  if (t < 256) {
    int tt = (int)t;
    if (tt < 64) bias192[tt] = b_res[tt];
    else if (tt < 128) bias192[tt] = 0.f;
    else if (tt < 192) bias192[tt] = b_l1[tt - 128];
    bias256[tt] = (tt < 128) ? 0.f : b_l2[tt - 128];
    return;
  }
  t -= 256;
  if (t < NN) { icnt[t] = 0; return; }
  t -= NN;
  if (t < (ll)NN * 8) { a_s[t] = 0.f; a_d[t] = 0.f; }
}

// ---------- CSR build ----------
__global__ void k_counti(const int* __restrict__ dst, int* __restrict__ icnt) {
  int e = blockIdx.x * 256 + threadIdx.x;
  if (e < NE) atomicAdd(&icnt[dst[e]], 1);
}

// single-block scan: 1024 threads x 20 items; also writes cur + dinv
__global__ __launch_bounds__(1024) void k_scan_all(
    const int* __restrict__ icnt, int* __restrict__ rowptr,
    int* __restrict__ cur, float* __restrict__ dinv) {
  __shared__ int sd[1024];
  const int PT = 20;
  int t = threadIdx.x;
  int i0 = t * PT;
  int cnt[PT];
  int sum = 0;
  #pragma unroll
  for (int j = 0; j < PT; j++) {
    int i = i0 + j;
    int v = (i < NN) ? icnt[i] + 1 : 0;   // +1 self loop
    cnt[j] = v; sum += v;
  }
  sd[t] = sum;
  __syncthreads();
  for (int o = 1; o < 1024; o <<= 1) {
    int u = (t >= o) ? sd[t - o] : 0;
    __syncthreads();
    sd[t] += u;
    __syncthreads();
  }
  int pre = sd[t] - sum;                  // exclusive prefix
  #pragma unroll
  for (int j = 0; j < PT; j++) {
    int i = i0 + j;
    if (i < NN) {
      rowptr[i] = pre;
      cur[i] = pre;
      dinv[i] = rsqrtf((float)cnt[j]);    // deg incl. self loop, >= 1
      pre += cnt[j];
    }
  }
  if (t == 1023) rowptr[NN] = NEF;
}

__global__ void k_scatter(const int* __restrict__ dst, int* __restrict__ cur,
                          int* __restrict__ eid) {
  int t = blockIdx.x * 256 + threadIdx.x;
  if (t >= NEF) return;
  int d = (t < NE) ? dst[t] : t - NE;
  int p = atomicAdd(&cur[d], 1);
  eid[p] = t;
}

// ---------- SAGE aggregation: shuffle-staged gather + mean + lin_r + relu (+res) --
template<int C, int STRIDE, bool ADD_RES>
__global__ __launch_bounds__(256) void k_sage_csr(
    const int* __restrict__ rowptr, const int* __restrict__ eid,
    const int* __restrict__ src, const ushort* __restrict__ feat,
    const ushort* __restrict__ linr, const ushort* __restrict__ resx,
    ushort* __restrict__ out)
{
  int node = blockIdx.x * 4 + (threadIdx.x >> 6);
  int lane = threadIdx.x & 63;
  if (node >= NN) return;
  int b = rowptr[node], e = rowptr[node + 1];
  float a0 = 0.f, a1 = 0.f;
  int n = 0;
  for (int base = b; base < e; base += 64) {
    int m = min(64, e - base);
    int sreg = -1;
    if (lane < m) {
      int ed = eid[base + lane];
      sreg = (ed < NE) ? src[ed] : -1;   // self loop excluded from SAGE mean
    }
    for (int i = 0; i < m; i++) {
      int s = __shfl(sreg, i);
      if (s >= 0) {
        a0 += b2f(feat[(ll)s * STRIDE + lane]);
        if (C == 128) a1 += b2f(feat[(ll)s * STRIDE + lane + 64]);
        n++;
      }
    }
  }
  float inv = 1.f / fmaxf((float)n, 1.f);
  {
    float v = a0 * inv + b2f(linr[(ll)node * STRIDE + lane]);
    v = fmaxf(v, 0.f);
    if (ADD_RES) v += b2f(resx[(ll)node * STRIDE + lane]);
    out[(ll)node * C + lane] = f2b(v);
  }
  if (C == 128) {
    float v = a1 * inv + b2f(linr[(ll)node * STRIDE + lane + 64]);
    v = fmaxf(v, 0.f);
    out[(ll)node * C + lane + 64] = f2b(v);
  }
}

// ---------- fused GAT: softmax (online, in-block) + gather + bias + relu ----------
__global__ __launch_bounds__(256) void k_gat(
    const int* __restrict__ rowptr, const int* __restrict__ eid,
    const int* __restrict__ src, const float* __restrict__ a_s,
    const float* __restrict__ a_d, const ushort4* __restrict__ hg4,
    const float* __restrict__ b_g, ushort4* __restrict__ gat4)
{
  __shared__ int   s_l[128];
  __shared__ float al[128 * 8];
  __shared__ float adl[8], mfin[8], sfin[8];
  int node = blockIdx.x;
  int t = threadIdx.x;
  int b = rowptr[node], e = rowptr[node + 1];
  if (t < 8) adl[t] = a_d[(ll)node * 8 + t];
  __syncthreads();

  // pass 1: per-head online max/sum (threads 0..7 own one head each)
  float m_run = -3.0e38f, s_run = 0.f;
  for (int c0 = b; c0 < e; c0 += 128) {
    int m = min(128, e - c0);
    if (t < m) { int ed = eid[c0 + t]; s_l[t] = (ed < NE) ? src[ed] : node; }
    __syncthreads();
    for (int idx = t; idx < m * 8; idx += 256) {
      int i = idx >> 3, hh = idx & 7;
      float v = a_s[(ll)s_l[i] * 8 + hh] + adl[hh];
      al[idx] = (v > 0.f) ? v : 0.2f * v;
    }
    __syncthreads();
    if (t < 8) {
      float cm = m_run;
      for (int i = 0; i < m; i++) cm = fmaxf(cm, al[i * 8 + t]);
      s_run *= __expf(m_run - cm);
      float cs = 0.f;
      for (int i = 0; i < m; i++) cs += __expf(al[i * 8 + t] - cm);
      s_run += cs;
      m_run = cm;
    }
    __syncthreads();
  }
  if (t < 8) { mfin[t] = m_run; sfin[t] = 1.f / s_run; }
  __syncthreads();

  // pass 2: alpha in LDS, gather
  int hh = t >> 5;                       // head for this thread's 4 channels
  float inv = sfin[hh];
  float ax = 0.f, ay = 0.f, az = 0.f, aw = 0.f;
  for (int c0 = b; c0 < e; c0 += 128) {
    int m = min(128, e - c0);
    if (t < m) { int ed = eid[c0 + t]; s_l[t] = (ed < NE) ? src[ed] : node; }
    __syncthreads();
    for (int idx = t; idx < m * 8; idx += 256) {
      int i = idx >> 3, h2 = idx & 7;
      float v = a_s[(ll)s_l[i] * 8 + h2] + adl[h2];
      v = (v > 0.f) ? v : 0.2f * v;
      al[idx] = __expf(v - mfin[h2]);
    }
    __syncthreads();
    for (int i = 0; i < m; i++) {
      int s = s_l[i];
      float a = al[i * 8 + hh];
      ushort4 v = hg4[(ll)s * 256 + t];
      ax = fmaf(a, b2f(v.x), ax);
      ay = fmaf(a, b2f(v.y), ay);
      az = fmaf(a, b2f(v.z), az);
      aw = fmaf(a, b2f(v.w), aw);
    }
    __syncthreads();
  }
  float4 bb = ((const float4*)b_g)[t];
  ushort4 o;
  o.x = f2b(fmaxf(fmaf(ax, inv, bb.x), 0.f));
  o.y = f2b(fmaxf(fmaf(ay, inv, bb.y), 0.f));
  o.z = f2b(fmaxf(fmaf(az, inv, bb.z), 0.f));
  o.w = f2b(fmaxf(fmaf(aw, inv, bb.w), 0.f));
  gat4[(ll)node * 256 + t] = o;
}

// ---------- GCN aggregation (shuffle-staged src+dinv); optional fused log_softmax --
template<int C, bool FUSE_LSM>
__global__ __launch_bounds__(256) void k_gcn_csr(
    const int* __restrict__ rowptr, const int* __restrict__ eid,
    const int* __restrict__ src, const float* __restrict__ dinv,
    const ushort* __restrict__ hw, const float* __restrict__ bias,
    void* __restrict__ outv)
{
  const int npb = 256 / C;
  int node = blockIdx.x * npb + threadIdx.x / C;
  int c = threadIdx.x & (C - 1);
  if (node >= NN) return;
  int b = rowptr[node], e = rowptr[node + 1];
  float acc = 0.f;
  for (int base = b; base < e; base += C) {
    int m = min(C, e - base);
    int sreg = 0;
    float dreg = 0.f;
    if (c < m) {
      int ed = eid[base + c];
      sreg = (ed < NE) ? src[ed] : node;
      dreg = dinv[sreg];
    }
    for (int i = 0; i < m; i++) {
      int s  = __shfl(sreg, i, C);
      float dv = __shfl(dreg, i, C);
      acc = fmaf(dv, b2f(hw[(ll)s * C + c]), acc);
    }
  }
  float v = acc * dinv[node] + bias[c];
  if (!FUSE_LSM) {
    ((ushort*)outv)[(ll)node * C + c] = f2b(v);
  } else {
    float mx = v;
    #pragma unroll
    for (int o = 16; o > 0; o >>= 1) mx = fmaxf(mx, __shfl_xor(mx, o, 32));
    float s = expf(v - mx);
    #pragma unroll
    for (int o = 16; o > 0; o >>= 1) s += __shfl_xor(s, o, 32);
    ((float*)outv)[(ll)node * C + c] = v - mx - logf(s);
  }
}

extern "C" void kernel_launch(void* const* d_in, const int* in_sizes, int n_in,
                              void* d_out, int out_size, void* d_ws, size_t ws_size,
                              hipStream_t stream) {
  const float* x     = (const float*)d_in[0];
  const int*   ei    = (const int*)d_in[1];
  const float* W_l1  = (const float*)d_in[2];
  const float* b_l1  = (const float*)d_in[3];
  const float* W_r1  = (const float*)d_in[4];
  const float* W_l2  = (const float*)d_in[5];
  const float* b_l2  = (const float*)d_in[6];
  const float* W_r2  = (const float*)d_in[7];
  const float* W_g   = (const float*)d_in[8];
  const float* att_s = (const float*)d_in[9];
  const float* att_d = (const float*)d_in[10];
  const float* b_g   = (const float*)d_in[11];
  const float* W_c1  = (const float*)d_in[12];
  const float* b_c1  = (const float*)d_in[13];
  const float* W_c2  = (const float*)d_in[14];
  const float* b_c2  = (const float*)d_in[15];
  const float* W_res = (const float*)d_in[16];
  const float* b_res = (const float*)d_in[17];
  const int* src = ei;
  const int* dst = ei + NE;
  float* out = (float*)d_out;

  // ---- workspace layout (4-byte units) ----
  float* Wf = (float*)d_ws;
  size_t off = 0;
  auto take = [&](size_t n) { float* p = Wf + off; off += (n + 3) & ~(size_t)3; return p; };
  ushort* xb    = (ushort*)take((size_t)NN * 128);   // x bf16 [NN,256]
  ushort* C192  = (ushort*)take((size_t)NN * 96);    // [resx|xw1|xr1]
  ushort* h1    = (ushort*)take((size_t)NN * 32);    // [NN,64]
  ushort* C256  = (ushort*)take((size_t)NN * 128);   // [hw2|hr2]
  ushort* h2    = (ushort*)take((size_t)NN * 64);    // [NN,128]
  ushort* hg    = (ushort*)take((size_t)NN * 512);   // [NN,1024]
  ushort* gat   = (ushort*)take((size_t)NN * 512);   // [NN,1024]
  ushort* hw64  = (ushort*)take((size_t)NN * 32);
  ushort* acc64 = (ushort*)take((size_t)NN * 32);
  ushort* hw32  = (ushort*)take((size_t)NN * 16);
  ushort* Bt192 = (ushort*)take(192 * 256 / 2);
  ushort* Bt256 = (ushort*)take(256 * 64 / 2);
  ushort* BtG   = (ushort*)take(1024 * 128 / 2);
  ushort* Btc1  = (ushort*)take(64 * 1024 / 2);
  ushort* Btc2  = (ushort*)take(32 * 64 / 2);
  float* bias192 = take(192);
  float* bias256 = take(256);
  int*   icnt   = (int*)take(NN);
  int*   rowptr = (int*)take(NN + 1);
  int*   cur    = (int*)take(NN);
  int*   eidb   = (int*)take(NEF);
  float* dinv   = take(NN);
  float* a_s    = take((size_t)NN * 8);
  float* a_d    = take((size_t)NN * 8);
  (void)ws_size; (void)in_sizes; (void)n_in; (void)out_size;

  auto nb = [](ll t) { return dim3((unsigned)((t + 255) / 256)); };

  // ---- setup (also zeroes icnt, a_s, a_d) ----
  Prep pp;
  int base = 0;
  auto ent = [&](int i, const float* W, ushort* Bt, int N_, int K_) {
    pp.e[i] = {W, Bt, N_, K_, base}; base += N_ * K_;
  };
  ent(0, W_res, Bt192,             64, 256);
  ent(1, W_l1,  Bt192 + 64 * 256,  64, 256);
  ent(2, W_r1,  Bt192 + 128 * 256, 64, 256);
  ent(3, W_l2,  Bt256,             128, 64);
  ent(4, W_r2,  Bt256 + 128 * 64,  128, 64);
  ent(5, W_g,   BtG,               1024, 128);
  ent(6, W_c1,  Btc1,              64, 1024);
  ent(7, W_c2,  Btc2,              32, 64);
  pp.total = base;
  k_setup<<<nb((ll)NN * 64 + base + 256 + NN + (ll)NN * 8), 256, 0, stream>>>(
      x, xb, pp, b_res, b_l1, b_l2, bias192, bias256, icnt, a_s, a_d);

  // ---- CSR build ----
  k_counti<<<nb(NE), 256, 0, stream>>>(dst, icnt);
  k_scan_all<<<1, 1024, 0, stream>>>(icnt, rowptr, cur, dinv);
  k_scatter<<<nb(NEF), 256, 0, stream>>>(dst, cur, eidb);

  // ---- SAGE1 (+residual): N=192 GEMM [resx|xw1|xr1] ----
  gemm_mfma<2, 2, false><<<dim3(3, 313), 256, 0, stream>>>(
      xb, Bt192, bias192, C192, NN, 192, 256, nullptr, nullptr, nullptr, nullptr);
  k_sage_csr<64, 192, true><<<nb((ll)NN * 64), 256, 0, stream>>>(
      rowptr, eidb, src, C192 + 64, C192 + 128, C192, h1);

  // ---- SAGE2: N=256 GEMM [hw2|hr2] ----
  gemm_mfma<2, 2, false><<<dim3(4, 313), 256, 0, stream>>>(
      h1, Bt256, bias256, C256, NN, 256, 64, nullptr, nullptr, nullptr, nullptr);
  k_sage_csr<128, 256, false><<<nb((ll)NN * 64), 256, 0, stream>>>(
      rowptr, eidb, src, C256, C256 + 128, nullptr, h2);

  // ---- GAT: GEMM with fused atomic score epilogue, then fused softmax+gather ----
  gemm_mfma<2, 4, true><<<dim3(8, 313), 256, 0, stream>>>(
      h2, BtG, nullptr, hg, NN, 1024, 128, att_s, att_d, a_s, a_d);
  k_gat<<<dim3(NN), 256, 0, stream>>>(
      rowptr, eidb, src, a_s, a_d, (const ushort4*)hg, b_g, (ushort4*)gat);

  // ---- GCN1 (16x16 wave tiles for wave-count) ----
  gemm_mfma<1, 1, false><<<dim3(2, 625), 256, 0, stream>>>(
      gat, Btc1, nullptr, hw64, NN, 64, 1024, nullptr, nullptr, nullptr, nullptr);
  k_gcn_csr<64, false><<<nb((ll)NN * 64), 256, 0, stream>>>(
      rowptr, eidb, src, dinv, hw64, b_c1, acc64);

  // ---- GCN2 + fused log_softmax ----
  gemm_mfma<1, 1, false><<<dim3(1, 625), 256, 0, stream>>>(
      acc64, Btc2, nullptr, hw32, NN, 32, 64, nullptr, nullptr, nullptr, nullptr);
  k_gcn_csr<32, true><<<nb((ll)NN * 32), 256, 0, stream>>>(
      rowptr, eidb, src, dinv, hw32, b_c2, out);
}

// Round 7
// 279.843 us; speedup vs baseline: 1.2528x; 1.2528x over previous
//
#include <hip/hip_runtime.h>

#define NN 20000
#define NE 160000
#define NEF 180000          // edges + self loops
#define NB1 ((NN + 255) / 256)   // 79 scan blocks

typedef long long ll;
typedef __attribute__((ext_vector_type(4))) float f32x4;
typedef __attribute__((ext_vector_type(8))) short s16x8;

// ---------- bf16 helpers (round-to-nearest-even) ----------
static __device__ __forceinline__ float b2f(ushort u) {
  return __uint_as_float(((unsigned)u) << 16);
}
static __device__ __forceinline__ ushort f2b(float f) {
  unsigned u = __float_as_uint(f);
  return (ushort)((u + 0x7fffu + ((u >> 16) & 1u)) >> 16);
}

// ---------- bf16 MFMA GEMM: C[M,N] = A[M,K] @ Bt[N,K]^T (+bias) ----------
// 4 waves in 2x2; wave tile = (16*MF) x (16*NF); no LDS, direct global frags.
// HEADED: A k-window slides per 128-col head (block-diagonal W_g apply):
//   A row read = A[row*lda + (bn>>7)*128 + k], k in [0,K).
template<int MF, int NF, bool HEADED, bool F32OUT, bool RELU>
__global__ __launch_bounds__(256) void gemm_mfma(
    const ushort* __restrict__ A, const ushort* __restrict__ Bt,
    const float* __restrict__ bias, void* __restrict__ Cv,
    int M, int N, int K, int lda)
{
  const int wid  = threadIdx.x >> 6;
  const int lane = threadIdx.x & 63;
  const int wr = wid >> 1, wc = wid & 1;
  const int bm = blockIdx.y * (32 * MF) + wr * (16 * MF);
  const int bn = blockIdx.x * (32 * NF) + wc * (16 * NF);
  const int lr = lane & 15;
  const int ko = (lane >> 4) * 8;
  const int koff = HEADED ? (bn >> 7) * 128 : 0;

  const ushort* pa[MF];
  const ushort* pb[NF];
  #pragma unroll
  for (int i = 0; i < MF; i++) {
    int r = min(bm + i * 16 + lr, M - 1);
    pa[i] = A + (ll)r * lda + koff + ko;
  }
  #pragma unroll
  for (int j = 0; j < NF; j++) {
    int c = min(bn + j * 16 + lr, N - 1);
    pb[j] = Bt + (ll)c * K + ko;
  }

  f32x4 acc[MF][NF];
  #pragma unroll
  for (int i = 0; i < MF; i++)
    #pragma unroll
    for (int j = 0; j < NF; j++) acc[i][j] = {0.f, 0.f, 0.f, 0.f};

  #pragma unroll 4
  for (int k = 0; k < K; k += 32) {
    s16x8 af[MF], bf[NF];
    #pragma unroll
    for (int i = 0; i < MF; i++) af[i] = *(const s16x8*)(pa[i] + k);
    #pragma unroll
    for (int j = 0; j < NF; j++) bf[j] = *(const s16x8*)(pb[j] + k);
    #pragma unroll
    for (int i = 0; i < MF; i++)
      #pragma unroll
      for (int j = 0; j < NF; j++)
        acc[i][j] = __builtin_amdgcn_mfma_f32_16x16x32_bf16(af[i], bf[j], acc[i][j], 0, 0, 0);
  }

  const int rq = (lane >> 4) * 4;
  #pragma unroll
  for (int i = 0; i < MF; i++) {
    #pragma unroll
    for (int j = 0; j < NF; j++) {
      int col = bn + j * 16 + lr;
      if (col >= N) continue;
      float bv = bias ? bias[col] : 0.f;
      int rbase = bm + i * 16 + rq;
      #pragma unroll
      for (int r = 0; r < 4; r++) {
        int row = rbase + r;
        if (row >= M) continue;
        float v = acc[i][j][r] + bv;
        if (RELU) v = fmaxf(v, 0.f);
        if (F32OUT) ((float*)Cv)[(ll)row * N + col] = v;
        else        ((ushort*)Cv)[(ll)row * N + col] = f2b(v);
      }
    }
  }
}

// ---------- fused setup: x cast, weight transpose+cast, bias packs, watt ----------
struct PrepEnt { const float* W; ushort* Bt; int N; int K; int base; };
struct Prep { PrepEnt e[8]; int total; };

__global__ void k_setup(const float* __restrict__ x, ushort* __restrict__ xb, Prep p,
                        const float* __restrict__ b_res, const float* __restrict__ b_l1,
                        const float* __restrict__ b_l2, float* __restrict__ bias192,
                        float* __restrict__ bias256,
                        const float* __restrict__ W_g, const float* __restrict__ att_s,
                        const float* __restrict__ att_d, ushort* __restrict__ watt_t) {
  ll t = (ll)blockIdx.x * 256 + threadIdx.x;
  const ll T0 = (ll)NN * 64;          // x cast: 4 floats each
  if (t < T0) {
    ll i = t * 4;
    float4 v = *(const float4*)(x + i);
    ushort4 o;
    o.x = f2b(v.x); o.y = f2b(v.y); o.z = f2b(v.z); o.w = f2b(v.w);
    *(ushort4*)(xb + i) = o;
    return;
  }
  t -= T0;
  if (t < p.total) {
    int tt = (int)t;
    #pragma unroll
    for (int i = 0; i < 8; i++) {
      int sz = p.e[i].N * p.e[i].K;
      if (tt >= p.e[i].base && tt < p.e[i].base + sz) {
        int loc = tt - p.e[i].base;
        int n = loc / p.e[i].K, k = loc - n * p.e[i].K;
        p.e[i].Bt[loc] = f2b(p.e[i].W[(ll)k * p.e[i].N + n]);
      }
    }
    return;
  }
  t -= p.total;
  if (t < 256) {
    int tt = (int)t;
    if (tt < 64) bias192[tt] = b_res[tt];
    else if (tt < 128) bias192[tt] = 0.f;
    else if (tt < 192) bias192[tt] = b_l1[tt - 128];
    bias256[tt] = (tt < 128) ? 0.f : b_l2[tt - 128];
    return;
  }
  t -= 256;
  if (t < 2048) {   // watt_t[col][k] = bf16( dot(W_g[k, h*128: ], att_{s|d}[h, :]) )
    int k = (int)t >> 4;
    int col = (int)t & 15;
    int h = col & 7;
    const float* av = (col < 8) ? (att_s + h * 128) : (att_d + h * 128);
    const float* wrow = W_g + (ll)k * 1024 + h * 128;
    float s = 0.f;
    for (int j = 0; j < 128; j++) s += wrow[j] * av[j];
    watt_t[col * 128 + k] = f2b(s);
  }
}

// ---------- CSR build ----------
__global__ void k_counti(const int* __restrict__ dst, int* __restrict__ icnt) {
  int e = blockIdx.x * 256 + threadIdx.x;
  if (e < NE) atomicAdd(&icnt[dst[e]], 1);
}

__global__ __launch_bounds__(256) void k_scan1(const int* __restrict__ icnt,
                                               int* __restrict__ rowptr,
                                               int* __restrict__ bsum) {
  __shared__ int sd[256];
  int t = threadIdx.x;
  int i = blockIdx.x * 256 + t;
  int v = (i < NN) ? icnt[i] + 1 : 0;   // +1 self loop
  sd[t] = v;
  __syncthreads();
  #pragma unroll
  for (int o = 1; o < 256; o <<= 1) {
    int u = (t >= o) ? sd[t - o] : 0;
    __syncthreads();
    sd[t] += u;
    __syncthreads();
  }
  if (i < NN) rowptr[i] = sd[t] - v;    // block-local exclusive
  if (t == 255) bsum[blockIdx.x] = sd[255];
}

__global__ __launch_bounds__(128) void k_scan2(const int* __restrict__ bsum,
                                               int* __restrict__ boff) {
  __shared__ int sd[128];
  int t = threadIdx.x;
  int v = (t < NB1) ? bsum[t] : 0;
  sd[t] = v;
  __syncthreads();
  #pragma unroll
  for (int o = 1; o < 128; o <<= 1) {
    int u = (t >= o) ? sd[t - o] : 0;
    __syncthreads();
    sd[t] += u;
    __syncthreads();
  }
  if (t < NB1) boff[t] = sd[t] - v;
}

__global__ void k_scan3(int* __restrict__ rowptr, const int* __restrict__ boff,
                        int* __restrict__ cur, const int* __restrict__ icnt,
                        float* __restrict__ dinv) {
  int i = blockIdx.x * 256 + threadIdx.x;
  if (i >= NN) return;
  int r = rowptr[i] + boff[i >> 8];
  rowptr[i] = r;
  cur[i] = r;
  dinv[i] = rsqrtf((float)icnt[i] + 1.0f);
  if (i == 0) rowptr[NN] = NEF;
}

__global__ void k_scatter(const int* __restrict__ dst, int* __restrict__ cur,
                          int* __restrict__ eid) {
  int t = blockIdx.x * 256 + threadIdx.x;
  if (t >= NEF) return;
  int d = (t < NE) ? dst[t] : t - NE;
  int p = atomicAdd(&cur[d], 1);
  eid[p] = t;
}

// ---------- SAGE aggregation: shuffle-staged gather + mean + lin_r + relu (+res) --
template<int C, int STRIDE, bool ADD_RES>
__global__ __launch_bounds__(256) void k_sage_csr(
    const int* __restrict__ rowptr, const int* __restrict__ eid,
    const int* __restrict__ src, const ushort* __restrict__ feat,
    const ushort* __restrict__ linr, const ushort* __restrict__ resx,
    ushort* __restrict__ out)
{
  int node = blockIdx.x * 4 + (threadIdx.x >> 6);
  int lane = threadIdx.x & 63;
  if (node >= NN) return;
  int b = rowptr[node], e = rowptr[node + 1];
  float a0 = 0.f, a1 = 0.f;
  int n = 0;
  for (int base = b; base < e; base += 64) {
    int m = min(64, e - base);
    int sreg = -1;
    if (lane < m) {
      int ed = eid[base + lane];
      sreg = (ed < NE) ? src[ed] : -1;   // self loop excluded from SAGE mean
    }
    for (int i = 0; i < m; i++) {
      int s = __shfl(sreg, i);
      if (s >= 0) {
        a0 += b2f(feat[(ll)s * STRIDE + lane]);
        if (C == 128) a1 += b2f(feat[(ll)s * STRIDE + lane + 64]);
        n++;
      }
    }
  }
  float inv = 1.f / fmaxf((float)n, 1.f);
  {
    float v = a0 * inv + b2f(linr[(ll)node * STRIDE + lane]);
    v = fmaxf(v, 0.f);
    if (ADD_RES) v += b2f(resx[(ll)node * STRIDE + lane]);
    out[(ll)node * C + lane] = f2b(v);
  }
  if (C == 128) {
    float v = a1 * inv + b2f(linr[(ll)node * STRIDE + lane + 64]);
    v = fmaxf(v, 0.f);
    out[(ll)node * C + lane + 64] = f2b(v);
  }
}

// ---------- GAT softmax: thread = (node, head); CSR 2-pass, no atomics ----------
// asd[n,16]: cols 0..7 = a_s per head, 8..15 = a_d per head.
__global__ void k_gat_softmax(const int* __restrict__ rowptr, const int* __restrict__ eid,
                              const int* __restrict__ src, const float* __restrict__ asd,
                              float* __restrict__ alpha, float* __restrict__ invden) {
  int t = blockIdx.x * 256 + threadIdx.x;
  if (t >= NN * 8) return;
  int node = t >> 3, h = t & 7;
  int b = rowptr[node], e = rowptr[node + 1];
  float ad = asd[(ll)node * 16 + 8 + h];
  float mx = -3.0e38f;
  for (int p = b; p < e; p++) {
    int ed = eid[p];
    int s = (ed < NE) ? src[ed] : node;
    float v = asd[(ll)s * 16 + h] + ad;
    v = (v > 0.f) ? v : 0.2f * v;
    mx = fmaxf(mx, v);
  }
  float sum = 0.f;
  for (int p = b; p < e; p++) {
    int ed = eid[p];
    int s = (ed < NE) ? src[ed] : node;
    float v = asd[(ll)s * 16 + h] + ad;
    v = (v > 0.f) ? v : 0.2f * v;
    float ex = expf(v - mx);
    alpha[(ll)p * 8 + h] = ex;
    sum += ex;
  }
  invden[t] = 1.f / sum;
}

// ---------- GAT aggregation in h2-space (128-dim): agg[n,h,c] = sum alpha*h2[src,c] --
__global__ __launch_bounds__(128) void k_gat_agg(
    const int* __restrict__ rowptr, const int* __restrict__ eid,
    const int* __restrict__ src, const float* __restrict__ alpha,
    const float* __restrict__ invden, const ushort* __restrict__ h2b,
    ushort* __restrict__ agg)
{
  __shared__ int s_l[64];
  __shared__ float al[64 * 8];
  __shared__ float inv_s[8];
  int node = blockIdx.x;
  int c = threadIdx.x;                 // channel 0..127
  int b = rowptr[node], e = rowptr[node + 1];
  if (c < 8) inv_s[c] = invden[node * 8 + c];
  float acc[8] = {0.f, 0.f, 0.f, 0.f, 0.f, 0.f, 0.f, 0.f};
  for (int c0 = b; c0 < e; c0 += 64) {
    int m = min(64, e - c0);
    if (c < m) { int ed = eid[c0 + c]; s_l[c] = (ed < NE) ? src[ed] : node; }
    for (int idx = c; idx < m * 8; idx += 128) al[idx] = alpha[(ll)c0 * 8 + idx];
    __syncthreads();
    for (int i = 0; i < m; i++) {
      float v = b2f(h2b[(ll)s_l[i] * 128 + c]);
      float4 aa = *(const float4*)&al[i * 8];
      float4 ab = *(const float4*)&al[i * 8 + 4];
      acc[0] = fmaf(aa.x, v, acc[0]);
      acc[1] = fmaf(aa.y, v, acc[1]);
      acc[2] = fmaf(aa.z, v, acc[2]);
      acc[3] = fmaf(aa.w, v, acc[3]);
      acc[4] = fmaf(ab.x, v, acc[4]);
      acc[5] = fmaf(ab.y, v, acc[5]);
      acc[6] = fmaf(ab.z, v, acc[6]);
      acc[7] = fmaf(ab.w, v, acc[7]);
    }
    __syncthreads();
  }
  #pragma unroll
  for (int h = 0; h < 8; h++)
    agg[(ll)node * 1024 + h * 128 + c] = f2b(acc[h] * inv_s[h]);
}

// ---------- GCN aggregation (shuffle-staged src+dinv); optional fused log_softmax --
template<int C, bool FUSE_LSM>
__global__ __launch_bounds__(256) void k_gcn_csr(
    const int* __restrict__ rowptr, const int* __restrict__ eid,
    const int* __restrict__ src, const float* __restrict__ dinv,
    const ushort* __restrict__ hw, const float* __restrict__ bias,
    void* __restrict__ outv)
{
  const int npb = 256 / C;
  int node = blockIdx.x * npb + threadIdx.x / C;
  int c = threadIdx.x & (C - 1);
  if (node >= NN) return;
  int b = rowptr[node], e = rowptr[node + 1];
  float acc = 0.f;
  for (int base = b; base < e; base += C) {
    int m = min(C, e - base);
    int sreg = 0;
    float dreg = 0.f;
    if (c < m) {
      int ed = eid[base + c];
      sreg = (ed < NE) ? src[ed] : node;
      dreg = dinv[sreg];
    }
    for (int i = 0; i < m; i++) {
      int s  = __shfl(sreg, i, C);
      float dv = __shfl(dreg, i, C);
      acc = fmaf(dv, b2f(hw[(ll)s * C + c]), acc);
    }
  }
  float v = acc * dinv[node] + bias[c];
  if (!FUSE_LSM) {
    ((ushort*)outv)[(ll)node * C + c] = f2b(v);
  } else {
    float mx = v;
    #pragma unroll
    for (int o = 16; o > 0; o >>= 1) mx = fmaxf(mx, __shfl_xor(mx, o, 32));
    float s = expf(v - mx);
    #pragma unroll
    for (int o = 16; o > 0; o >>= 1) s += __shfl_xor(s, o, 32);
    ((float*)outv)[(ll)node * C + c] = v - mx - logf(s);
  }
}

extern "C" void kernel_launch(void* const* d_in, const int* in_sizes, int n_in,
                              void* d_out, int out_size, void* d_ws, size_t ws_size,
                              hipStream_t stream) {
  const float* x     = (const float*)d_in[0];
  const int*   ei    = (const int*)d_in[1];
  const float* W_l1  = (const float*)d_in[2];
  const float* b_l1  = (const float*)d_in[3];
  const float* W_r1  = (const float*)d_in[4];
  const float* W_l2  = (const float*)d_in[5];
  const float* b_l2  = (const float*)d_in[6];
  const float* W_r2  = (const float*)d_in[7];
  const float* W_g   = (const float*)d_in[8];
  const float* att_s = (const float*)d_in[9];
  const float* att_d = (const float*)d_in[10];
  const float* b_g   = (const float*)d_in[11];
  const float* W_c1  = (const float*)d_in[12];
  const float* b_c1  = (const float*)d_in[13];
  const float* W_c2  = (const float*)d_in[14];
  const float* b_c2  = (const float*)d_in[15];
  const float* W_res = (const float*)d_in[16];
  const float* b_res = (const float*)d_in[17];
  const int* src = ei;
  const int* dst = ei + NE;
  float* out = (float*)d_out;

  // ---- workspace layout (4-byte units) ----
  float* Wf = (float*)d_ws;
  size_t off = 0;
  auto take = [&](size_t n) { float* p = Wf + off; off += (n + 3) & ~(size_t)3; return p; };
  ushort* xb    = (ushort*)take((size_t)NN * 128);   // x bf16 [NN,256]
  ushort* C192  = (ushort*)take((size_t)NN * 96);    // [resx|xw1|xr1]
  ushort* h1    = (ushort*)take((size_t)NN * 32);    // [NN,64]
  ushort* C256  = (ushort*)take((size_t)NN * 128);   // [hw2|hr2]
  ushort* h2    = (ushort*)take((size_t)NN * 64);    // [NN,128]
  ushort* agg   = (ushort*)take((size_t)NN * 512);   // [NN,8,128] alpha-weighted h2
  ushort* gat   = (ushort*)take((size_t)NN * 512);   // [NN,1024]
  ushort* hw64  = (ushort*)take((size_t)NN * 32);
  ushort* acc64 = (ushort*)take((size_t)NN * 32);
  ushort* hw32  = (ushort*)take((size_t)NN * 16);
  ushort* Bt192 = (ushort*)take(192 * 256 / 2);
  ushort* Bt256 = (ushort*)take(256 * 64 / 2);
  ushort* BtG   = (ushort*)take(1024 * 128 / 2);
  ushort* Btc1  = (ushort*)take(64 * 1024 / 2);
  ushort* Btc2  = (ushort*)take(32 * 64 / 2);
  ushort* watt_t= (ushort*)take(16 * 128 / 2);       // [16,128] transposed W_g@att
  float* bias192 = take(192);
  float* bias256 = take(256);
  int*   icnt   = (int*)take(NN);
  int*   rowptr = (int*)take(NN + 1);
  int*   cur    = (int*)take(NN);
  int*   eidb   = (int*)take(NEF);
  int*   bsum   = (int*)take(NB1);
  int*   boff   = (int*)take(NB1);
  float* dinv   = take(NN);
  float* asd    = take((size_t)NN * 16);
  float* alpha  = take((size_t)NEF * 8);
  float* invden = take((size_t)NN * 8);
  (void)ws_size; (void)in_sizes; (void)n_in; (void)out_size;

  auto nb = [](ll t) { return dim3((unsigned)((t + 255) / 256)); };

  // ---- CSR build ----
  hipMemsetAsync(icnt, 0, NN * sizeof(int), stream);
  k_counti<<<nb(NE), 256, 0, stream>>>(dst, icnt);
  k_scan1<<<NB1, 256, 0, stream>>>(icnt, rowptr, bsum);
  k_scan2<<<1, 128, 0, stream>>>(bsum, boff);
  k_scan3<<<nb(NN), 256, 0, stream>>>(rowptr, boff, cur, icnt, dinv);
  k_scatter<<<nb(NEF), 256, 0, stream>>>(dst, cur, eidb);

  // ---- setup: cast x, weights -> bf16 transposed, bias packs, watt ----
  Prep pp;
  int base = 0;
  auto ent = [&](int i, const float* W, ushort* Bt, int N_, int K_) {
    pp.e[i] = {W, Bt, N_, K_, base}; base += N_ * K_;
  };
  ent(0, W_res, Bt192,             64, 256);
  ent(1, W_l1,  Bt192 + 64 * 256,  64, 256);
  ent(2, W_r1,  Bt192 + 128 * 256, 64, 256);
  ent(3, W_l2,  Bt256,             128, 64);
  ent(4, W_r2,  Bt256 + 128 * 64,  128, 64);
  ent(5, W_g,   BtG,               1024, 128);
  ent(6, W_c1,  Btc1,              64, 1024);
  ent(7, W_c2,  Btc2,              32, 64);
  pp.total = base;
  k_setup<<<nb((ll)NN * 64 + base + 256 + 2048), 256, 0, stream>>>(
      x, xb, pp, b_res, b_l1, b_l2, bias192, bias256, W_g, att_s, att_d, watt_t);

  // ---- SAGE1 (+residual): N=192 GEMM [resx|xw1|xr1] ----
  gemm_mfma<2, 2, false, false, false><<<dim3(3, 313), 256, 0, stream>>>(
      xb, Bt192, bias192, C192, NN, 192, 256, 256);
  k_sage_csr<64, 192, true><<<nb((ll)NN * 64), 256, 0, stream>>>(
      rowptr, eidb, src, C192 + 64, C192 + 128, C192, h1);

  // ---- SAGE2: N=256 GEMM [hw2|hr2] ----
  gemm_mfma<2, 2, false, false, false><<<dim3(4, 313), 256, 0, stream>>>(
      h1, Bt256, bias256, C256, NN, 256, 64, 64);
  k_sage_csr<128, 256, false><<<nb((ll)NN * 64), 256, 0, stream>>>(
      rowptr, eidb, src, C256, C256 + 128, nullptr, h2);

  // ---- GAT: scores via tiny N=16 GEMM (f32 out), softmax, h2-space aggregation,
  //      then block-diagonal W_g apply (+b_g, relu) ----
  gemm_mfma<2, 1, false, true, false><<<dim3(1, 313), 256, 0, stream>>>(
      h2, watt_t, nullptr, asd, NN, 16, 128, 128);
  k_gat_softmax<<<nb((ll)NN * 8), 256, 0, stream>>>(
      rowptr, eidb, src, asd, alpha, invden);
  k_gat_agg<<<dim3(NN), 128, 0, stream>>>(
      rowptr, eidb, src, alpha, invden, h2, agg);
  gemm_mfma<2, 2, true, false, true><<<dim3(16, 313), 256, 0, stream>>>(
      agg, BtG, b_g, gat, NN, 1024, 128, 1024);

  // ---- GCN1 ----
  gemm_mfma<2, 2, false, false, false><<<dim3(1, 313), 256, 0, stream>>>(
      gat, Btc1, nullptr, hw64, NN, 64, 1024, 1024);
  k_gcn_csr<64, false><<<nb((ll)NN * 64), 256, 0, stream>>>(
      rowptr, eidb, src, dinv, hw64, b_c1, acc64);

  // ---- GCN2 + fused log_softmax ----
  gemm_mfma<2, 2, false, false, false><<<dim3(1, 313), 256, 0, stream>>>(
      acc64, Btc2, nullptr, hw32, NN, 32, 64, 64);
  k_gcn_csr<32, true><<<nb((ll)NN * 32), 256, 0, stream>>>(
      rowptr, eidb, src, dinv, hw32, b_c2, out);
}

// Round 8
// 260.230 us; speedup vs baseline: 1.3472x; 1.0754x over previous
//
#include <hip/hip_runtime.h>

#define NN 20000
#define NE 160000
#define NEF 180000          // edges + self loops
#define NB1 ((NN + 255) / 256)   // 79 scan blocks

typedef long long ll;
typedef __attribute__((ext_vector_type(4))) float f32x4;
typedef __attribute__((ext_vector_type(8))) short s16x8;

// ---------- bf16 helpers (round-to-nearest-even) ----------
static __device__ __forceinline__ float b2f(ushort u) {
  return __uint_as_float(((unsigned)u) << 16);
}
static __device__ __forceinline__ ushort f2b(float f) {
  unsigned u = __float_as_uint(f);
  return (ushort)((u + 0x7fffu + ((u >> 16) & 1u)) >> 16);
}

// ---------- bf16 MFMA GEMM: C[M,N] = A[M,K] @ Bt[N,K]^T (+bias) ----------
// 4 waves in 2x2; wave tile = (16*MF) x (16*NF); no LDS; compile-time K.
template<int MF, int NF, int K, bool F32OUT>
__global__ __launch_bounds__(256) void gemm_mfma(
    const ushort* __restrict__ A, const ushort* __restrict__ Bt,
    const float* __restrict__ bias, void* __restrict__ Cv,
    int M, int N, int lda)
{
  const int wid  = threadIdx.x >> 6;
  const int lane = threadIdx.x & 63;
  const int wr = wid >> 1, wc = wid & 1;
  const int bm = blockIdx.y * (32 * MF) + wr * (16 * MF);
  const int bn = blockIdx.x * (32 * NF) + wc * (16 * NF);
  const int lr = lane & 15;
  const int ko = (lane >> 4) * 8;

  const ushort* pa[MF];
  const ushort* pb[NF];
  #pragma unroll
  for (int i = 0; i < MF; i++) {
    int r = min(bm + i * 16 + lr, M - 1);
    pa[i] = A + (ll)r * lda + ko;
  }
  #pragma unroll
  for (int j = 0; j < NF; j++) {
    int c = min(bn + j * 16 + lr, N - 1);
    pb[j] = Bt + (ll)c * K + ko;
  }

  f32x4 acc[MF][NF];
  #pragma unroll
  for (int i = 0; i < MF; i++)
    #pragma unroll
    for (int j = 0; j < NF; j++) acc[i][j] = {0.f, 0.f, 0.f, 0.f};

  #pragma unroll
  for (int k = 0; k < K; k += 32) {
    s16x8 af[MF], bf[NF];
    #pragma unroll
    for (int i = 0; i < MF; i++) af[i] = *(const s16x8*)(pa[i] + k);
    #pragma unroll
    for (int j = 0; j < NF; j++) bf[j] = *(const s16x8*)(pb[j] + k);
    #pragma unroll
    for (int i = 0; i < MF; i++)
      #pragma unroll
      for (int j = 0; j < NF; j++)
        acc[i][j] = __builtin_amdgcn_mfma_f32_16x16x32_bf16(af[i], bf[j], acc[i][j], 0, 0, 0);
  }

  const int rq = (lane >> 4) * 4;
  #pragma unroll
  for (int i = 0; i < MF; i++) {
    #pragma unroll
    for (int j = 0; j < NF; j++) {
      int col = bn + j * 16 + lr;
      if (col >= N) continue;
      float bv = bias ? bias[col] : 0.f;
      int rbase = bm + i * 16 + rq;
      #pragma unroll
      for (int r = 0; r < 4; r++) {
        int row = rbase + r;
        if (row >= M) continue;
        float v = acc[i][j][r] + bv;
        if (F32OUT) ((float*)Cv)[(ll)row * N + col] = v;
        else        ((ushort*)Cv)[(ll)row * N + col] = f2b(v);
      }
    }
  }
}

// ---------- fused GAT-apply + GCN1 GEMM ----------
// hw64 = relu(agg @ blockdiag(W_g) + b_g) @ W_c1, never materializing gat.
// 256 thr = 4 waves; BM=32 rows/block; wave w owns 16-col strip of both the
// 64-col gat tile and the 64-col output. Double-buffered LDS gat tile.
__global__ __launch_bounds__(256) void k_gat_apply_gcn1(
    const ushort* __restrict__ agg,   // [NN,1024] bf16 (8 heads x 128)
    const ushort* __restrict__ BtG,   // [1024,128]: BtG[c*128+k] = W_g[k,c]
    const ushort* __restrict__ Btc1,  // [64,1024]:  Btc1[n*1024+k] = W_c1[k,n]
    const float* __restrict__ b_g,    // [1024]
    ushort* __restrict__ hw64)        // [NN,64] bf16
{
  __shared__ ushort gt[2][32][72];    // +16B row pad -> 2-way bank alias (free)
  const int wc   = threadIdx.x >> 6;  // wave = col strip 0..3
  const int lane = threadIdx.x & 63;
  const int bm = blockIdx.x * 32;
  const int lr = lane & 15;
  const int ko = (lane >> 4) * 8;
  const int rq = (lane >> 4) * 4;

  const ushort* pa0 = agg + (ll)min(bm + lr,      NN - 1) * 1024 + ko;
  const ushort* pa1 = agg + (ll)min(bm + 16 + lr, NN - 1) * 1024 + ko;

  f32x4 o0 = {0.f, 0.f, 0.f, 0.f}, o1 = o0;

  #pragma unroll 2
  for (int ct = 0; ct < 16; ct++) {
    const int koff = (ct >> 1) * 128;          // per-head A k-window
    const int cg = ct * 64 + wc * 16 + lr;     // global gat col for this lane
    const ushort* pb = BtG + (ll)cg * 128 + ko;
    f32x4 g0 = {0.f, 0.f, 0.f, 0.f}, g1 = g0;
    #pragma unroll
    for (int k = 0; k < 128; k += 32) {
      s16x8 a0 = *(const s16x8*)(pa0 + koff + k);
      s16x8 a1 = *(const s16x8*)(pa1 + koff + k);
      s16x8 bb = *(const s16x8*)(pb + k);
      g0 = __builtin_amdgcn_mfma_f32_16x16x32_bf16(a0, bb, g0, 0, 0, 0);
      g1 = __builtin_amdgcn_mfma_f32_16x16x32_bf16(a1, bb, g1, 0, 0, 0);
    }
    float bv = b_g[cg];
    #pragma unroll
    for (int r = 0; r < 4; r++) {
      gt[ct & 1][rq + r][wc * 16 + lr]      = f2b(fmaxf(g0[r] + bv, 0.f));
      gt[ct & 1][16 + rq + r][wc * 16 + lr] = f2b(fmaxf(g1[r] + bv, 0.f));
    }
    __syncthreads();
    const ushort* qb = Btc1 + (ll)(wc * 16 + lr) * 1024 + ct * 64 + ko;
    #pragma unroll
    for (int k = 0; k < 64; k += 32) {
      s16x8 a0 = *(const s16x8*)&gt[ct & 1][lr][k + ko];
      s16x8 a1 = *(const s16x8*)&gt[ct & 1][16 + lr][k + ko];
      s16x8 bb = *(const s16x8*)(qb + k);
      o0 = __builtin_amdgcn_mfma_f32_16x16x32_bf16(a0, bb, o0, 0, 0, 0);
      o1 = __builtin_amdgcn_mfma_f32_16x16x32_bf16(a1, bb, o1, 0, 0, 0);
    }
  }
  int col = wc * 16 + lr;
  #pragma unroll
  for (int r = 0; r < 4; r++) {
    int row0 = bm + rq + r, row1 = bm + 16 + rq + r;
    if (row0 < NN) hw64[(ll)row0 * 64 + col] = f2b(o0[r]);
    if (row1 < NN) hw64[(ll)row1 * 64 + col] = f2b(o1[r]);
  }
}

// ---------- fused setup: x cast, weight transpose+cast, bias packs, watt ----------
struct PrepEnt { const float* W; ushort* Bt; int N; int K; int base; };
struct Prep { PrepEnt e[8]; int total; };

__global__ void k_setup(const float* __restrict__ x, ushort* __restrict__ xb, Prep p,
                        const float* __restrict__ b_res, const float* __restrict__ b_l1,
                        const float* __restrict__ b_l2, float* __restrict__ bias192,
                        float* __restrict__ bias256,
                        const float* __restrict__ W_g, const float* __restrict__ att_s,
                        const float* __restrict__ att_d, ushort* __restrict__ watt_t) {
  ll t = (ll)blockIdx.x * 256 + threadIdx.x;
  const ll T0 = (ll)NN * 64;          // x cast: 4 floats each
  if (t < T0) {
    ll i = t * 4;
    float4 v = *(const float4*)(x + i);
    ushort4 o;
    o.x = f2b(v.x); o.y = f2b(v.y); o.z = f2b(v.z); o.w = f2b(v.w);
    *(ushort4*)(xb + i) = o;
    return;
  }
  t -= T0;
  if (t < p.total) {
    int tt = (int)t;
    #pragma unroll
    for (int i = 0; i < 8; i++) {
      int sz = p.e[i].N * p.e[i].K;
      if (tt >= p.e[i].base && tt < p.e[i].base + sz) {
        int loc = tt - p.e[i].base;
        int n = loc / p.e[i].K, k = loc - n * p.e[i].K;
        p.e[i].Bt[loc] = f2b(p.e[i].W[(ll)k * p.e[i].N + n]);
      }
    }
    return;
  }
  t -= p.total;
  if (t < 256) {
    int tt = (int)t;
    if (tt < 64) bias192[tt] = b_res[tt];
    else if (tt < 128) bias192[tt] = 0.f;
    else if (tt < 192) bias192[tt] = b_l1[tt - 128];
    bias256[tt] = (tt < 128) ? 0.f : b_l2[tt - 128];
    return;
  }
  t -= 256;
  if (t < 2048) {   // watt_t[col][k] = bf16( dot(W_g[k, h*128: ], att_{s|d}[h, :]) )
    int k = (int)t >> 4;
    int col = (int)t & 15;
    int h = col & 7;
    const float* av = (col < 8) ? (att_s + h * 128) : (att_d + h * 128);
    const float* wrow = W_g + (ll)k * 1024 + h * 128;
    float s = 0.f;
    for (int j = 0; j < 128; j++) s += wrow[j] * av[j];
    watt_t[col * 128 + k] = f2b(s);
  }
}

// ---------- CSR build ----------
__global__ void k_counti(const int* __restrict__ dst, int* __restrict__ icnt) {
  int e = blockIdx.x * 256 + threadIdx.x;
  if (e < NE) atomicAdd(&icnt[dst[e]], 1);
}

__global__ __launch_bounds__(256) void k_scan1(const int* __restrict__ icnt,
                                               int* __restrict__ rowptr,
                                               int* __restrict__ bsum) {
  __shared__ int sd[256];
  int t = threadIdx.x;
  int i = blockIdx.x * 256 + t;
  int v = (i < NN) ? icnt[i] + 1 : 0;   // +1 self loop
  sd[t] = v;
  __syncthreads();
  #pragma unroll
  for (int o = 1; o < 256; o <<= 1) {
    int u = (t >= o) ? sd[t - o] : 0;
    __syncthreads();
    sd[t] += u;
    __syncthreads();
  }
  if (i < NN) rowptr[i] = sd[t] - v;    // block-local exclusive
  if (t == 255) bsum[blockIdx.x] = sd[255];
}

__global__ __launch_bounds__(128) void k_scan2(const int* __restrict__ bsum,
                                               int* __restrict__ boff) {
  __shared__ int sd[128];
  int t = threadIdx.x;
  int v = (t < NB1) ? bsum[t] : 0;
  sd[t] = v;
  __syncthreads();
  #pragma unroll
  for (int o = 1; o < 128; o <<= 1) {
    int u = (t >= o) ? sd[t - o] : 0;
    __syncthreads();
    sd[t] += u;
    __syncthreads();
  }
  if (t < NB1) boff[t] = sd[t] - v;
}

__global__ void k_scan3(int* __restrict__ rowptr, const int* __restrict__ boff,
                        int* __restrict__ cur, const int* __restrict__ icnt,
                        float* __restrict__ dinv) {
  int i = blockIdx.x * 256 + threadIdx.x;
  if (i >= NN) return;
  int r = rowptr[i] + boff[i >> 8];
  rowptr[i] = r;
  cur[i] = r;
  dinv[i] = rsqrtf((float)icnt[i] + 1.0f);
  if (i == 0) rowptr[NN] = NEF;
}

__global__ void k_scatter(const int* __restrict__ dst, int* __restrict__ cur,
                          int* __restrict__ eid) {
  int t = blockIdx.x * 256 + threadIdx.x;
  if (t >= NEF) return;
  int d = (t < NE) ? dst[t] : t - NE;
  int p = atomicAdd(&cur[d], 1);
  eid[p] = t;
}

// ---------- SAGE aggregation: shuffle-staged gather + mean + lin_r + relu (+res) --
template<int C, int STRIDE, bool ADD_RES>
__global__ __launch_bounds__(256) void k_sage_csr(
    const int* __restrict__ rowptr, const int* __restrict__ eid,
    const int* __restrict__ src, const ushort* __restrict__ feat,
    const ushort* __restrict__ linr, const ushort* __restrict__ resx,
    ushort* __restrict__ out)
{
  int node = blockIdx.x * 4 + (threadIdx.x >> 6);
  int lane = threadIdx.x & 63;
  if (node >= NN) return;
  int b = rowptr[node], e = rowptr[node + 1];
  float a0 = 0.f, a1 = 0.f;
  int n = 0;
  for (int base = b; base < e; base += 64) {
    int m = min(64, e - base);
    int sreg = -1;
    if (lane < m) {
      int ed = eid[base + lane];
      sreg = (ed < NE) ? src[ed] : -1;   // self loop excluded from SAGE mean
    }
    for (int i = 0; i < m; i++) {
      int s = __shfl(sreg, i);
      if (s >= 0) {
        a0 += b2f(feat[(ll)s * STRIDE + lane]);
        if (C == 128) a1 += b2f(feat[(ll)s * STRIDE + lane + 64]);
        n++;
      }
    }
  }
  float inv = 1.f / fmaxf((float)n, 1.f);
  {
    float v = a0 * inv + b2f(linr[(ll)node * STRIDE + lane]);
    v = fmaxf(v, 0.f);
    if (ADD_RES) v += b2f(resx[(ll)node * STRIDE + lane]);
    out[(ll)node * C + lane] = f2b(v);
  }
  if (C == 128) {
    float v = a1 * inv + b2f(linr[(ll)node * STRIDE + lane + 64]);
    v = fmaxf(v, 0.f);
    out[(ll)node * C + lane + 64] = f2b(v);
  }
}

// ---------- GAT softmax: thread = (node, head); CSR 2-pass, no atomics ----------
// asd[n,16]: cols 0..7 = a_s per head, 8..15 = a_d per head.
__global__ void k_gat_softmax(const int* __restrict__ rowptr, const int* __restrict__ eid,
                              const int* __restrict__ src, const float* __restrict__ asd,
                              float* __restrict__ alpha, float* __restrict__ invden) {
  int t = blockIdx.x * 256 + threadIdx.x;
  if (t >= NN * 8) return;
  int node = t >> 3, h = t & 7;
  int b = rowptr[node], e = rowptr[node + 1];
  float ad = asd[(ll)node * 16 + 8 + h];
  float mx = -3.0e38f;
  for (int p = b; p < e; p++) {
    int ed = eid[p];
    int s = (ed < NE) ? src[ed] : node;
    float v = asd[(ll)s * 16 + h] + ad;
    v = (v > 0.f) ? v : 0.2f * v;
    mx = fmaxf(mx, v);
  }
  float sum = 0.f;
  for (int p = b; p < e; p++) {
    int ed = eid[p];
    int s = (ed < NE) ? src[ed] : node;
    float v = asd[(ll)s * 16 + h] + ad;
    v = (v > 0.f) ? v : 0.2f * v;
    float ex = expf(v - mx);
    alpha[(ll)p * 8 + h] = ex;
    sum += ex;
  }
  invden[t] = 1.f / sum;
}

// ---------- GAT aggregation in h2-space: agg[n,h,c] = (1/den) sum alpha*h2[src,c] --
__global__ __launch_bounds__(128) void k_gat_agg(
    const int* __restrict__ rowptr, const int* __restrict__ eid,
    const int* __restrict__ src, const float* __restrict__ alpha,
    const float* __restrict__ invden, const ushort* __restrict__ h2b,
    ushort* __restrict__ agg)
{
  __shared__ int s_l[64];
  __shared__ float al[64 * 8];
  __shared__ float inv_s[8];
  int node = blockIdx.x;
  int c = threadIdx.x;                 // channel 0..127
  int b = rowptr[node], e = rowptr[node + 1];
  if (c < 8) inv_s[c] = invden[node * 8 + c];
  float acc[8] = {0.f, 0.f, 0.f, 0.f, 0.f, 0.f, 0.f, 0.f};
  for (int c0 = b; c0 < e; c0 += 64) {
    int m = min(64, e - c0);
    if (c < m) { int ed = eid[c0 + c]; s_l[c] = (ed < NE) ? src[ed] : node; }
    for (int idx = c; idx < m * 8; idx += 128) al[idx] = alpha[(ll)c0 * 8 + idx];
    __syncthreads();
    for (int i = 0; i < m; i++) {
      float v = b2f(h2b[(ll)s_l[i] * 128 + c]);
      float4 aa = *(const float4*)&al[i * 8];
      float4 ab = *(const float4*)&al[i * 8 + 4];
      acc[0] = fmaf(aa.x, v, acc[0]);
      acc[1] = fmaf(aa.y, v, acc[1]);
      acc[2] = fmaf(aa.z, v, acc[2]);
      acc[3] = fmaf(aa.w, v, acc[3]);
      acc[4] = fmaf(ab.x, v, acc[4]);
      acc[5] = fmaf(ab.y, v, acc[5]);
      acc[6] = fmaf(ab.z, v, acc[6]);
      acc[7] = fmaf(ab.w, v, acc[7]);
    }
    __syncthreads();
  }
  #pragma unroll
  for (int h = 0; h < 8; h++)
    agg[(ll)node * 1024 + h * 128 + c] = f2b(acc[h] * inv_s[h]);
}

// ---------- GCN aggregation (shuffle-staged src+dinv); optional fused log_softmax --
template<int C, bool FUSE_LSM>
__global__ __launch_bounds__(256) void k_gcn_csr(
    const int* __restrict__ rowptr, const int* __restrict__ eid,
    const int* __restrict__ src, const float* __restrict__ dinv,
    const ushort* __restrict__ hw, const float* __restrict__ bias,
    void* __restrict__ outv)
{
  const int npb = 256 / C;
  int node = blockIdx.x * npb + threadIdx.x / C;
  int c = threadIdx.x & (C - 1);
  if (node >= NN) return;
  int b = rowptr[node], e = rowptr[node + 1];
  float acc = 0.f;
  for (int base = b; base < e; base += C) {
    int m = min(C, e - base);
    int sreg = 0;
    float dreg = 0.f;
    if (c < m) {
      int ed = eid[base + c];
      sreg = (ed < NE) ? src[ed] : node;
      dreg = dinv[sreg];
    }
    for (int i = 0; i < m; i++) {
      int s  = __shfl(sreg, i, C);
      float dv = __shfl(dreg, i, C);
      acc = fmaf(dv, b2f(hw[(ll)s * C + c]), acc);
    }
  }
  float v = acc * dinv[node] + bias[c];
  if (!FUSE_LSM) {
    ((ushort*)outv)[(ll)node * C + c] = f2b(v);
  } else {
    float mx = v;
    #pragma unroll
    for (int o = 16; o > 0; o >>= 1) mx = fmaxf(mx, __shfl_xor(mx, o, 32));
    float s = expf(v - mx);
    #pragma unroll
    for (int o = 16; o > 0; o >>= 1) s += __shfl_xor(s, o, 32);
    ((float*)outv)[(ll)node * C + c] = v - mx - logf(s);
  }
}

extern "C" void kernel_launch(void* const* d_in, const int* in_sizes, int n_in,
                              void* d_out, int out_size, void* d_ws, size_t ws_size,
                              hipStream_t stream) {
  const float* x     = (const float*)d_in[0];
  const int*   ei    = (const int*)d_in[1];
  const float* W_l1  = (const float*)d_in[2];
  const float* b_l1  = (const float*)d_in[3];
  const float* W_r1  = (const float*)d_in[4];
  const float* W_l2  = (const float*)d_in[5];
  const float* b_l2  = (const float*)d_in[6];
  const float* W_r2  = (const float*)d_in[7];
  const float* W_g   = (const float*)d_in[8];
  const float* att_s = (const float*)d_in[9];
  const float* att_d = (const float*)d_in[10];
  const float* b_g   = (const float*)d_in[11];
  const float* W_c1  = (const float*)d_in[12];
  const float* b_c1  = (const float*)d_in[13];
  const float* W_c2  = (const float*)d_in[14];
  const float* b_c2  = (const float*)d_in[15];
  const float* W_res = (const float*)d_in[16];
  const float* b_res = (const float*)d_in[17];
  const int* src = ei;
  const int* dst = ei + NE;
  float* out = (float*)d_out;

  // ---- workspace layout (4-byte units) ----
  float* Wf = (float*)d_ws;
  size_t off = 0;
  auto take = [&](size_t n) { float* p = Wf + off; off += (n + 3) & ~(size_t)3; return p; };
  ushort* xb    = (ushort*)take((size_t)NN * 128);   // x bf16 [NN,256]
  ushort* C192  = (ushort*)take((size_t)NN * 96);    // [resx|xw1|xr1]
  ushort* h1    = (ushort*)take((size_t)NN * 32);    // [NN,64]
  ushort* C256  = (ushort*)take((size_t)NN * 128);   // [hw2|hr2]
  ushort* h2    = (ushort*)take((size_t)NN * 64);    // [NN,128]
  ushort* agg   = (ushort*)take((size_t)NN * 512);   // [NN,8,128] alpha-weighted h2
  ushort* hw64  = (ushort*)take((size_t)NN * 32);
  ushort* acc64 = (ushort*)take((size_t)NN * 32);
  ushort* hw32  = (ushort*)take((size_t)NN * 16);
  ushort* Bt192 = (ushort*)take(192 * 256 / 2);
  ushort* Bt256 = (ushort*)take(256 * 64 / 2);
  ushort* BtG   = (ushort*)take(1024 * 128 / 2);
  ushort* Btc1  = (ushort*)take(64 * 1024 / 2);
  ushort* Btc2  = (ushort*)take(32 * 64 / 2);
  ushort* watt_t= (ushort*)take(16 * 128 / 2);       // [16,128] transposed W_g@att
  float* bias192 = take(192);
  float* bias256 = take(256);
  int*   icnt   = (int*)take(NN);
  int*   rowptr = (int*)take(NN + 1);
  int*   cur    = (int*)take(NN);
  int*   eidb   = (int*)take(NEF);
  int*   bsum   = (int*)take(NB1);
  int*   boff   = (int*)take(NB1);
  float* dinv   = take(NN);
  float* asd    = take((size_t)NN * 16);
  float* alpha  = take((size_t)NEF * 8);
  float* invden = take((size_t)NN * 8);
  (void)ws_size; (void)in_sizes; (void)n_in; (void)out_size;

  auto nb = [](ll t) { return dim3((unsigned)((t + 255) / 256)); };

  // ---- CSR build ----
  hipMemsetAsync(icnt, 0, NN * sizeof(int), stream);
  k_counti<<<nb(NE), 256, 0, stream>>>(dst, icnt);
  k_scan1<<<NB1, 256, 0, stream>>>(icnt, rowptr, bsum);
  k_scan2<<<1, 128, 0, stream>>>(bsum, boff);
  k_scan3<<<nb(NN), 256, 0, stream>>>(rowptr, boff, cur, icnt, dinv);
  k_scatter<<<nb(NEF), 256, 0, stream>>>(dst, cur, eidb);

  // ---- setup: cast x, weights -> bf16 transposed, bias packs, watt ----
  Prep pp;
  int base = 0;
  auto ent = [&](int i, const float* W, ushort* Bt, int N_, int K_) {
    pp.e[i] = {W, Bt, N_, K_, base}; base += N_ * K_;
  };
  ent(0, W_res, Bt192,             64, 256);
  ent(1, W_l1,  Bt192 + 64 * 256,  64, 256);
  ent(2, W_r1,  Bt192 + 128 * 256, 64, 256);
  ent(3, W_l2,  Bt256,             128, 64);
  ent(4, W_r2,  Bt256 + 128 * 64,  128, 64);
  ent(5, W_g,   BtG,               1024, 128);
  ent(6, W_c1,  Btc1,              64, 1024);
  ent(7, W_c2,  Btc2,              32, 64);
  pp.total = base;
  k_setup<<<nb((ll)NN * 64 + base + 256 + 2048), 256, 0, stream>>>(
      x, xb, pp, b_res, b_l1, b_l2, bias192, bias256, W_g, att_s, att_d, watt_t);

  // ---- SAGE1 (+residual): N=192 GEMM [resx|xw1|xr1] ----
  gemm_mfma<2, 2, 256, false><<<dim3(3, 313), 256, 0, stream>>>(
      xb, Bt192, bias192, C192, NN, 192, 256);
  k_sage_csr<64, 192, true><<<nb((ll)NN * 64), 256, 0, stream>>>(
      rowptr, eidb, src, C192 + 64, C192 + 128, C192, h1);

  // ---- SAGE2: N=256 GEMM [hw2|hr2] ----
  gemm_mfma<2, 2, 64, false><<<dim3(4, 313), 256, 0, stream>>>(
      h1, Bt256, bias256, C256, NN, 256, 64);
  k_sage_csr<128, 256, false><<<nb((ll)NN * 64), 256, 0, stream>>>(
      rowptr, eidb, src, C256, C256 + 128, nullptr, h2);

  // ---- GAT: scores via tiny N=16 GEMM (f32 out), softmax, h2-space aggregation,
  //      then fused block-diagonal W_g apply + GCN1 GEMM ----
  gemm_mfma<2, 1, 128, true><<<dim3(1, 313), 256, 0, stream>>>(
      h2, watt_t, nullptr, asd, NN, 16, 128);
  k_gat_softmax<<<nb((ll)NN * 8), 256, 0, stream>>>(
      rowptr, eidb, src, asd, alpha, invden);
  k_gat_agg<<<dim3(NN), 128, 0, stream>>>(
      rowptr, eidb, src, alpha, invden, h2, agg);
  k_gat_apply_gcn1<<<dim3(625), 256, 0, stream>>>(agg, BtG, Btc1, b_g, hw64);
  k_gcn_csr<64, false><<<nb((ll)NN * 64), 256, 0, stream>>>(
      rowptr, eidb, src, dinv, hw64, b_c1, acc64);

  // ---- GCN2 + fused log_softmax ----
  gemm_mfma<2, 1, 64, false><<<dim3(1, 313), 256, 0, stream>>>(
      acc64, Btc2, nullptr, hw32, NN, 32, 64);
  k_gcn_csr<32, true><<<nb((ll)NN * 32), 256, 0, stream>>>(
      rowptr, eidb, src, dinv, hw32, b_c2, out);
}